// Round 8
// baseline (443.784 us; speedup 1.0000x reference)
//
#include <hip/hip_runtime.h>
#include <hip/hip_bf16.h>

#define N_NODES 100000
#define N_EDGES 1600000
#define IN_C 128
#define C 64            // hid_c == out_c
#define SCAN_NB 25      // ceil(N_NODES / 4096)

__device__ __forceinline__ float bfu2f(unsigned short u) {
    return __uint_as_float(((unsigned int)u) << 16);
}
__device__ __forceinline__ unsigned short f2bfu(float f) {
    __hip_bfloat16 h = __float2bfloat16(f);
    unsigned short u; __builtin_memcpy(&u, &h, 2); return u;
}
__device__ __forceinline__ float load_f(const void* p, int i, int f32) {
    return f32 ? ((const float*)p)[i] : bfu2f(((const unsigned short*)p)[i]);
}
__device__ __forceinline__ int load_idx(const void* ei, size_t i, int i64) {
    return i64 ? (int)((const long long*)ei)[i] : ((const int*)ei)[i];
}

// ---- runtime dtype detection (R3 confirmed bf16+int32; kept for safety) ---
__global__ __launch_bounds__(256) void k_detect(
    const uint4* __restrict__ x4, const int* __restrict__ ei32,
    int* __restrict__ flags)
{
    __shared__ int cff, cnz;
    int t = threadIdx.x;
    if (t == 0) { cff = 0; cnz = 0; }
    __syncthreads();
    int lff = 0;
    #pragma unroll
    for (int j = 0; j < 16; ++j) {               // 4096 uint4 = 64K ushorts
        uint4 w = x4[t + j * 256];
        unsigned int a[4] = {w.x, w.y, w.z, w.w};
        #pragma unroll
        for (int q = 0; q < 4; ++q) {
            if ((a[q] & 0x00007F80u) == 0x00007F80u) lff++;
            if ((a[q] & 0x7F800000u) == 0x7F800000u) lff++;
        }
    }
    int lnz = 0;
    for (int i = t; i < 2048; i += 256)
        if (ei32[2 * i + 1] != 0) lnz++;
    if (lff) atomicAdd(&cff, lff);
    if (lnz) atomicAdd(&cnz, lnz);
    __syncthreads();
    if (t == 0) {
        flags[0] = (cff > 0) ? 1 : 0;   // 1 = fp32 floats
        flags[1] = (cnz == 0) ? 1 : 0;  // 1 = int64 indices
    }
}

// ---- CSR pass A: degree count + within-segment position (ONE atomic/edge) -
__global__ __launch_bounds__(256) void k_hist(
    const void* __restrict__ ei, const int* __restrict__ flags,
    int* __restrict__ cnt, unsigned short* __restrict__ pos)
{
    int e = blockIdx.x * 256 + threadIdx.x;
    int d = load_idx(ei, (size_t)N_EDGES + e, flags[1]);
    pos[e] = (unsigned short)atomicAdd(&cnt[d], 1);
}

// ---- CSR pass B1: per-block sums of cnt (coalesced) -----------------------
__global__ __launch_bounds__(256) void k_scan1(
    const int* __restrict__ cnt, int* __restrict__ bsum)
{
    __shared__ int red[256];
    int t = threadIdx.x, b = blockIdx.x;
    int base = b * 4096;
    int s = 0;
    #pragma unroll
    for (int j = 0; j < 16; ++j) {
        int i = base + j * 256 + t;
        if (i < N_NODES) s += cnt[i];
    }
    red[t] = s;
    #pragma unroll
    for (int off = 128; off > 0; off >>= 1) {
        __syncthreads();
        if (t < off) red[t] += red[t + off];
    }
    if (t == 0) bsum[b] = red[0];
}

// ---- CSR pass B2: per-block exclusive scan -> row_ptr ---------------------
__global__ __launch_bounds__(256) void k_scan3(
    const int* __restrict__ cnt, const int* __restrict__ bsum,
    int* __restrict__ row_ptr)
{
    __shared__ int tsum[256];
    __shared__ int off_sh;
    int t = threadIdx.x, b = blockIdx.x;
    if (t == 0) {
        int o = 0;
        for (int i = 0; i < b; ++i) o += bsum[i];
        off_sh = o;
        if (b == 0) row_ptr[N_NODES] = N_EDGES;   // total is a constant
    }
    int base = b * 4096 + t * 16;
    int v[16], s = 0;
    #pragma unroll
    for (int j = 0; j < 16; ++j) {
        int i = base + j;
        v[j] = (i < N_NODES) ? cnt[i] : 0;
        s += v[j];
    }
    tsum[t] = s;
    #pragma unroll
    for (int off = 1; off < 256; off <<= 1) {
        __syncthreads();
        int val = (t >= off) ? tsum[t - off] : 0;
        __syncthreads();
        tsum[t] += val;
    }
    __syncthreads();
    int run = off_sh + (t ? tsum[t - 1] : 0);
    #pragma unroll
    for (int j = 0; j < 16; ++j) {
        int i = base + j;
        if (i < N_NODES) { row_ptr[i] = run; run += v[j]; }
    }
}

// ---- CSR pass C: scatter {src, raw exp} — NO atomics ----------------------
__global__ __launch_bounds__(256) void k_scatter(
    const void* __restrict__ ea, const void* __restrict__ ei,
    const int* __restrict__ flags, const int* __restrict__ row_ptr,
    const unsigned short* __restrict__ pos, int2* __restrict__ srt)
{
    int e = blockIdx.x * 256 + threadIdx.x;
    int s = load_idx(ei, (size_t)e, flags[1]);
    int d = load_idx(ei, (size_t)N_EDGES + e, flags[1]);
    float w = expf(load_f(ea, e, flags[0]));     // unnormalized
    int p = row_ptr[d] + pos[e];
    srt[p] = make_int2(s, __float_as_int(w));
}

// ---- GEMM1: xw[n,c] = sum_k x[n,k] * W1[c,k] ------------------------------
// bf16 mode: xw stored as bf16 (halves msg gather traffic). f32 fallback: f32.
#define W1_STRIDE (IN_C + 4)   // 132
__global__ __launch_bounds__(256) void k_gemm1(
    const void* __restrict__ x, const void* __restrict__ W,
    const int* __restrict__ flags, void* __restrict__ xw)
{
    __shared__ float Wls[C * W1_STRIDE];
    __shared__ float xs[32 * IN_C];
    int t = threadIdx.x;
    int f32 = flags[0];
    size_t xbase = (size_t)blockIdx.x * 32 * IN_C;
    if (f32) {
        const float* xp = (const float*)x + xbase;
        #pragma unroll
        for (int j = 0; j < 16; ++j) { int i = t + j * 256; xs[i] = xp[i]; }
        const float* wp = (const float*)W;
        #pragma unroll
        for (int j = 0; j < 32; ++j) {
            int i = t + j * 256;
            Wls[(i >> 7) * W1_STRIDE + (i & 127)] = wp[i];
        }
    } else {
        const unsigned int* xp = (const unsigned int*)((const unsigned short*)x + xbase);
        #pragma unroll
        for (int j = 0; j < 8; ++j) {            // 2048 uints = 4096 bf16
            int i = t + j * 256;
            unsigned int v = xp[i];
            xs[2 * i]     = bfu2f((unsigned short)(v & 0xffff));
            xs[2 * i + 1] = bfu2f((unsigned short)(v >> 16));
        }
        const unsigned short* wp = (const unsigned short*)W;
        #pragma unroll
        for (int j = 0; j < 32; ++j) {
            int i = t + j * 256;
            Wls[(i >> 7) * W1_STRIDE + (i & 127)] = bfu2f(wp[i]);
        }
    }
    __syncthreads();
    int col = t & 63, wv = t >> 6;
    const float* wr = Wls + col * W1_STRIDE;
    const float* xr = xs + wv * 8 * IN_C;
    float acc[8];
    #pragma unroll
    for (int n = 0; n < 8; ++n) acc[n] = 0.f;
    #pragma unroll
    for (int kk = 0; kk < IN_C / 4; ++kk) {
        float4 w4 = *(const float4*)(wr + kk * 4);
        #pragma unroll
        for (int n = 0; n < 8; ++n) {
            float4 x4 = *(const float4*)(xr + n * IN_C + kk * 4);
            acc[n] += x4.x * w4.x + x4.y * w4.y + x4.z * w4.z + x4.w * w4.w;
        }
    }
    size_t obase = (size_t)blockIdx.x * 32 * C + wv * 8 * C + col;
    if (f32) {
        float* op = (float*)xw;
        #pragma unroll
        for (int n = 0; n < 8; ++n) op[obase + n * C] = acc[n];
    } else {
        unsigned short* op = (unsigned short*)xw;
        #pragma unroll
        for (int n = 0; n < 8; ++n) op[obase + n * C] = f2bfu(acc[n]);
    }
}

// ---- GEMM2: xw2[n,c] = sum_k h[n,k] * W2[c,k]  (h bf16 in fast path) ------
#define W2_STRIDE (C + 4)      // 68
__global__ __launch_bounds__(256) void k_gemm2(
    const void* __restrict__ h, const void* __restrict__ W,
    const int* __restrict__ flags, void* __restrict__ xw)
{
    __shared__ float Wls[C * W2_STRIDE];
    __shared__ float xs[32 * C];
    int t = threadIdx.x;
    int f32 = flags[0];
    size_t xbase = (size_t)blockIdx.x * 32 * C;
    if (f32) {
        const float* hp = (const float*)h + xbase;
        #pragma unroll
        for (int j = 0; j < 8; ++j) { int i = t + j * 256; xs[i] = hp[i]; }
        const float* wp = (const float*)W;
        #pragma unroll
        for (int j = 0; j < 16; ++j) {
            int i = t + j * 256;
            Wls[(i >> 6) * W2_STRIDE + (i & 63)] = wp[i];
        }
    } else {
        const unsigned int* hp = (const unsigned int*)((const unsigned short*)h + xbase);
        #pragma unroll
        for (int j = 0; j < 4; ++j) {            // 1024 uints = 2048 bf16
            int i = t + j * 256;
            unsigned int v = hp[i];
            xs[2 * i]     = bfu2f((unsigned short)(v & 0xffff));
            xs[2 * i + 1] = bfu2f((unsigned short)(v >> 16));
        }
        const unsigned short* wp = (const unsigned short*)W;
        #pragma unroll
        for (int j = 0; j < 16; ++j) {
            int i = t + j * 256;
            Wls[(i >> 6) * W2_STRIDE + (i & 63)] = bfu2f(wp[i]);
        }
    }
    __syncthreads();
    int col = t & 63, wv = t >> 6;
    const float* wr = Wls + col * W2_STRIDE;
    const float* xr = xs + wv * 8 * C;
    float acc[8];
    #pragma unroll
    for (int n = 0; n < 8; ++n) acc[n] = 0.f;
    #pragma unroll
    for (int kk = 0; kk < C / 4; ++kk) {
        float4 w4 = *(const float4*)(wr + kk * 4);
        #pragma unroll
        for (int n = 0; n < 8; ++n) {
            float4 x4 = *(const float4*)(xr + n * C + kk * 4);
            acc[n] += x4.x * w4.x + x4.y * w4.y + x4.z * w4.z + x4.w * w4.w;
        }
    }
    size_t obase = (size_t)blockIdx.x * 32 * C + wv * 8 * C + col;
    if (f32) {
        float* op = (float*)xw;
        #pragma unroll
        for (int n = 0; n < 8; ++n) op[obase + n * C] = acc[n];
    } else {
        unsigned short* op = (unsigned short*)xw;
        #pragma unroll
        for (int n = 0; n < 8; ++n) op[obase + n * C] = f2bfu(acc[n]);
    }
}

// ---- fused msg+update: wave per dst; self-normalizing ---------------------
// out = sigmoid( (Σ exp_e·xw[src_e]) / (Σ exp_e) + xw[d] + b )
// bf16 fast path: 2 edges/iter (half-wave each, dword bf16x2 loads),
// cross-half shfl_xor combine; output always bf16 (h1 and final d_out).
__global__ __launch_bounds__(256) void k_msg_csr(
    const void* __restrict__ xw, const int2* __restrict__ srt,
    const int* __restrict__ row_ptr, const void* __restrict__ b,
    const int* __restrict__ flags, void* __restrict__ outp, int out_is_final)
{
    int d = blockIdx.x * 4 + (threadIdx.x >> 6);
    int lane = threadIdx.x & 63;
    int beg = row_ptr[d], end = row_ptr[d + 1];
    if (!flags[0]) {
        const unsigned int* xwp = (const unsigned int*)xw;   // 32 uints/row
        int half = lane >> 5, li = lane & 31;
        float accx = 0.f, accy = 0.f, asum = 0.f;
        int j = beg;
        for (; j + 4 <= end; j += 4) {
            int2 pa = srt[j + half], pb = srt[j + 2 + half];
            float wa = __int_as_float(pa.y), wb = __int_as_float(pb.y);
            unsigned int va = xwp[(size_t)pa.x * 32 + li];
            unsigned int vb = xwp[(size_t)pb.x * 32 + li];
            accx += wa * bfu2f((unsigned short)(va & 0xffff))
                  + wb * bfu2f((unsigned short)(vb & 0xffff));
            accy += wa * bfu2f((unsigned short)(va >> 16))
                  + wb * bfu2f((unsigned short)(vb >> 16));
            asum += wa + wb;
        }
        for (; j + 2 <= end; j += 2) {
            int2 p = srt[j + half];
            float w = __int_as_float(p.y);
            unsigned int v = xwp[(size_t)p.x * 32 + li];
            accx += w * bfu2f((unsigned short)(v & 0xffff));
            accy += w * bfu2f((unsigned short)(v >> 16));
            asum += w;
        }
        if (j < end && half == 0) {
            int2 p = srt[j];
            float w = __int_as_float(p.y);
            unsigned int v = xwp[(size_t)p.x * 32 + li];
            accx += w * bfu2f((unsigned short)(v & 0xffff));
            accy += w * bfu2f((unsigned short)(v >> 16));
            asum += w;
        }
        accx += __shfl_xor(accx, 32);
        accy += __shfl_xor(accy, 32);
        asum += __shfl_xor(asum, 32);
        float inv = (end > beg) ? 1.f / asum : 0.f;
        unsigned int sv = xwp[(size_t)d * 32 + li];
        const unsigned short* bp = (const unsigned short*)b;
        float v0 = accx * inv + bfu2f((unsigned short)(sv & 0xffff)) + bfu2f(bp[2 * li]);
        float v1 = accy * inv + bfu2f((unsigned short)(sv >> 16))    + bfu2f(bp[2 * li + 1]);
        float r0 = 1.f / (1.f + expf(-v0));
        float r1 = 1.f / (1.f + expf(-v1));
        if (half == 0) {
            unsigned int packed = (unsigned int)f2bfu(r0) | ((unsigned int)f2bfu(r1) << 16);
            ((unsigned int*)outp)[(size_t)d * 32 + li] = packed;
        }
    } else {
        const float* xwp = (const float*)xw;
        float acc = 0.f, asum = 0.f;
        int j = beg;
        for (; j + 4 <= end; j += 4) {
            int2 p0 = srt[j], p1 = srt[j + 1], p2 = srt[j + 2], p3 = srt[j + 3];
            float w0 = __int_as_float(p0.y), w1 = __int_as_float(p1.y);
            float w2 = __int_as_float(p2.y), w3 = __int_as_float(p3.y);
            acc += w0 * xwp[(size_t)p0.x * C + lane]
                 + w1 * xwp[(size_t)p1.x * C + lane]
                 + w2 * xwp[(size_t)p2.x * C + lane]
                 + w3 * xwp[(size_t)p3.x * C + lane];
            asum += (w0 + w1) + (w2 + w3);
        }
        for (; j < end; ++j) {
            int2 p = srt[j];
            float w = __int_as_float(p.y);
            acc += w * xwp[(size_t)p.x * C + lane];
            asum += w;
        }
        float m = (end > beg) ? acc / asum : 0.f;
        float v = m + xwp[(size_t)d * C + lane] + ((const float*)b)[lane];
        float r = 1.f / (1.f + expf(-v));
        size_t oi = (size_t)d * C + lane;
        if (out_is_final) ((float*)outp)[oi] = r;
        else              ((float*)outp)[oi] = r;
    }
}

extern "C" void kernel_launch(void* const* d_in, const int* in_sizes, int n_in,
                              void* d_out, int out_size, void* d_ws, size_t ws_size,
                              hipStream_t stream) {
    const void* x  = d_in[0];
    const void* ei = d_in[1];
    const void* ea = d_in[2];
    const void* W1 = d_in[3];
    const void* b1 = d_in[4];
    const void* W2 = d_in[5];
    const void* b2 = d_in[6];

    char* base = (char*)d_ws;
    int*            flags   = (int*)base;                 // 256 B
    int*            cnt     = (int*)(base + 256);         // N
    int*            row_ptr = (int*)(base + 400256);      // N+1 (+pad)
    unsigned short* pos     = (unsigned short*)(base + 800272);  // E (2B)
    int*            bsum    = (int*)(base + 4000272);     // 25 (+pad)
    int2*           srt     = (int2*)(base + 4000528);    // E (8B-aligned)
    void*           xw      = (void*)(base + 16800528);   // N*64 (f32 worst case)
    void*           h1      = (void*)(base + 42400528);   // N*64
    // total ws use ≈ 68 MB

    k_detect<<<1, 256, 0, stream>>>((const uint4*)x, (const int*)ei, flags);
    hipMemsetAsync(cnt, 0, 400000, stream);

    // CSR build: count+pos (1 atomic/edge), scan, atomic-free scatter
    k_hist<<<N_EDGES / 256, 256, 0, stream>>>(ei, flags, cnt, pos);
    k_scan1<<<SCAN_NB, 256, 0, stream>>>(cnt, bsum);
    k_scan3<<<SCAN_NB, 256, 0, stream>>>(cnt, bsum, row_ptr);
    k_scatter<<<N_EDGES / 256, 256, 0, stream>>>(ea, ei, flags, row_ptr, pos, srt);

    // layer 1
    k_gemm1<<<N_NODES / 32, 256, 0, stream>>>(x, W1, flags, xw);
    k_msg_csr<<<N_NODES / 4, 256, 0, stream>>>(xw, srt, row_ptr, b1, flags, h1, 0);

    // layer 2
    k_gemm2<<<N_NODES / 32, 256, 0, stream>>>(h1, W2, flags, xw);
    k_msg_csr<<<N_NODES / 4, 256, 0, stream>>>(xw, srt, row_ptr, b2, flags, d_out, 1);
}

// Round 9
// 413.558 us; speedup vs baseline: 1.0731x; 1.0731x over previous
//
#include <hip/hip_runtime.h>
#include <hip/hip_bf16.h>

#define N_NODES 100000
#define N_EDGES 1600000
#define IN_C 128
#define C 64            // hid_c == out_c
#define SCAN_NB 25      // ceil(N_NODES / 4096)

__device__ __forceinline__ float bfu2f(unsigned short u) {
    return __uint_as_float(((unsigned int)u) << 16);
}
__device__ __forceinline__ unsigned short f2bfu(float f) {
    __hip_bfloat16 h = __float2bfloat16(f);
    unsigned short u; __builtin_memcpy(&u, &h, 2); return u;
}
__device__ __forceinline__ float load_f(const void* p, int i, int f32) {
    return f32 ? ((const float*)p)[i] : bfu2f(((const unsigned short*)p)[i]);
}
__device__ __forceinline__ int load_idx(const void* ei, size_t i, int i64) {
    return i64 ? (int)((const long long*)ei)[i] : ((const int*)ei)[i];
}

// ---- runtime dtype detection (R8 counters confirmed fp32+int32) -----------
__global__ __launch_bounds__(256) void k_detect(
    const uint4* __restrict__ x4, const int* __restrict__ ei32,
    int* __restrict__ flags)
{
    __shared__ int cff, cnz;
    int t = threadIdx.x;
    if (t == 0) { cff = 0; cnz = 0; }
    __syncthreads();
    int lff = 0;
    #pragma unroll
    for (int j = 0; j < 16; ++j) {               // 16384 dwords of x
        uint4 w = x4[t + j * 256];
        unsigned int a[4] = {w.x, w.y, w.z, w.w};
        #pragma unroll
        for (int q = 0; q < 4; ++q) {
            // fp32 data: low mantissa half as pseudo-bf16 exponent hits 0xFF
            // w.p. 1/256 per dword; bf16 pairs never have exp==0xFF (no inf/NaN)
            if ((a[q] & 0x00007F80u) == 0x00007F80u) lff++;
            if ((a[q] & 0x7F800000u) == 0x7F800000u) lff++;
        }
    }
    int lnz = 0;
    for (int i = t; i < 2048; i += 256)
        if (ei32[2 * i + 1] != 0) lnz++;
    if (lff) atomicAdd(&cff, lff);
    if (lnz) atomicAdd(&cnz, lnz);
    __syncthreads();
    if (t == 0) {
        flags[0] = (cff > 0) ? 1 : 0;   // 1 = fp32 floats (confirmed on HW)
        flags[1] = (cnz == 0) ? 1 : 0;  // 1 = int64 indices (HW: int32)
    }
}

// ---- CSR pass A: degree count + within-segment position (ONE atomic/edge) -
__global__ __launch_bounds__(256) void k_hist(
    const void* __restrict__ ei, const int* __restrict__ flags,
    int* __restrict__ cnt, unsigned short* __restrict__ pos)
{
    int e = blockIdx.x * 256 + threadIdx.x;
    int d = load_idx(ei, (size_t)N_EDGES + e, flags[1]);
    pos[e] = (unsigned short)atomicAdd(&cnt[d], 1);
}

// ---- CSR pass B1: per-block sums of cnt (coalesced) -----------------------
__global__ __launch_bounds__(256) void k_scan1(
    const int* __restrict__ cnt, int* __restrict__ bsum)
{
    __shared__ int red[256];
    int t = threadIdx.x, b = blockIdx.x;
    int base = b * 4096;
    int s = 0;
    #pragma unroll
    for (int j = 0; j < 16; ++j) {
        int i = base + j * 256 + t;
        if (i < N_NODES) s += cnt[i];
    }
    red[t] = s;
    #pragma unroll
    for (int off = 128; off > 0; off >>= 1) {
        __syncthreads();
        if (t < off) red[t] += red[t + off];
    }
    if (t == 0) bsum[b] = red[0];
}

// ---- CSR pass B2: per-block exclusive scan -> row_ptr ---------------------
__global__ __launch_bounds__(256) void k_scan3(
    const int* __restrict__ cnt, const int* __restrict__ bsum,
    int* __restrict__ row_ptr)
{
    __shared__ int tsum[256];
    __shared__ int off_sh;
    int t = threadIdx.x, b = blockIdx.x;
    if (t == 0) {
        int o = 0;
        for (int i = 0; i < b; ++i) o += bsum[i];
        off_sh = o;
        if (b == 0) row_ptr[N_NODES] = N_EDGES;   // total is a constant
    }
    int base = b * 4096 + t * 16;
    int v[16], s = 0;
    #pragma unroll
    for (int j = 0; j < 16; ++j) {
        int i = base + j;
        v[j] = (i < N_NODES) ? cnt[i] : 0;
        s += v[j];
    }
    tsum[t] = s;
    #pragma unroll
    for (int off = 1; off < 256; off <<= 1) {
        __syncthreads();
        int val = (t >= off) ? tsum[t - off] : 0;
        __syncthreads();
        tsum[t] += val;
    }
    __syncthreads();
    int run = off_sh + (t ? tsum[t - 1] : 0);
    #pragma unroll
    for (int j = 0; j < 16; ++j) {
        int i = base + j;
        if (i < N_NODES) { row_ptr[i] = run; run += v[j]; }
    }
}

// ---- CSR pass C: scatter {src, raw exp} — NO atomics ----------------------
__global__ __launch_bounds__(256) void k_scatter(
    const void* __restrict__ ea, const void* __restrict__ ei,
    const int* __restrict__ flags, const int* __restrict__ row_ptr,
    const unsigned short* __restrict__ pos, int2* __restrict__ srt)
{
    int e = blockIdx.x * 256 + threadIdx.x;
    int s = load_idx(ei, (size_t)e, flags[1]);
    int d = load_idx(ei, (size_t)N_EDGES + e, flags[1]);
    float w = expf(load_f(ea, e, flags[0]));     // unnormalized
    int p = row_ptr[d] + pos[e];
    srt[p] = make_int2(s, __float_as_int(w));
}

// ---- GEMM1: xw[n,c] = sum_k x[n,k] * W1[c,k]; OUTPUT ALWAYS bf16 ----------
#define W1_STRIDE (IN_C + 4)   // 132
__global__ __launch_bounds__(256) void k_gemm1(
    const void* __restrict__ x, const void* __restrict__ W,
    const int* __restrict__ flags, unsigned short* __restrict__ xw)
{
    __shared__ float Wls[C * W1_STRIDE];
    __shared__ float xs[32 * IN_C];
    int t = threadIdx.x;
    int f32 = flags[0];
    size_t xbase = (size_t)blockIdx.x * 32 * IN_C;
    if (f32) {
        const float* xp = (const float*)x + xbase;
        #pragma unroll
        for (int j = 0; j < 16; ++j) { int i = t + j * 256; xs[i] = xp[i]; }
        const float* wp = (const float*)W;
        #pragma unroll
        for (int j = 0; j < 32; ++j) {
            int i = t + j * 256;
            Wls[(i >> 7) * W1_STRIDE + (i & 127)] = wp[i];
        }
    } else {
        const unsigned int* xp = (const unsigned int*)((const unsigned short*)x + xbase);
        #pragma unroll
        for (int j = 0; j < 8; ++j) {
            int i = t + j * 256;
            unsigned int v = xp[i];
            xs[2 * i]     = bfu2f((unsigned short)(v & 0xffff));
            xs[2 * i + 1] = bfu2f((unsigned short)(v >> 16));
        }
        const unsigned short* wp = (const unsigned short*)W;
        #pragma unroll
        for (int j = 0; j < 32; ++j) {
            int i = t + j * 256;
            Wls[(i >> 7) * W1_STRIDE + (i & 127)] = bfu2f(wp[i]);
        }
    }
    __syncthreads();
    int col = t & 63, wv = t >> 6;
    const float* wr = Wls + col * W1_STRIDE;
    const float* xr = xs + wv * 8 * IN_C;
    float acc[8];
    #pragma unroll
    for (int n = 0; n < 8; ++n) acc[n] = 0.f;
    #pragma unroll
    for (int kk = 0; kk < IN_C / 4; ++kk) {
        float4 w4 = *(const float4*)(wr + kk * 4);
        #pragma unroll
        for (int n = 0; n < 8; ++n) {
            float4 x4 = *(const float4*)(xr + n * IN_C + kk * 4);
            acc[n] += x4.x * w4.x + x4.y * w4.y + x4.z * w4.z + x4.w * w4.w;
        }
    }
    size_t obase = (size_t)blockIdx.x * 32 * C + wv * 8 * C + col;
    #pragma unroll
    for (int n = 0; n < 8; ++n) xw[obase + n * C] = f2bfu(acc[n]);
}

// ---- GEMM2: h (bf16 internal) @ W2 -> xw (bf16 internal) ------------------
#define W2_STRIDE (C + 4)      // 68
__global__ __launch_bounds__(256) void k_gemm2(
    const unsigned int* __restrict__ h, const void* __restrict__ W,
    const int* __restrict__ flags, unsigned short* __restrict__ xw)
{
    __shared__ float Wls[C * W2_STRIDE];
    __shared__ float xs[32 * C];
    int t = threadIdx.x;
    size_t dwbase = (size_t)blockIdx.x * 32 * 32;   // 32 rows x 32 dwords
    #pragma unroll
    for (int j = 0; j < 4; ++j) {
        int i = t + j * 256;
        unsigned int v = h[dwbase + i];
        xs[2 * i]     = bfu2f((unsigned short)(v & 0xffff));
        xs[2 * i + 1] = bfu2f((unsigned short)(v >> 16));
    }
    if (flags[0]) {
        const float* wp = (const float*)W;
        #pragma unroll
        for (int j = 0; j < 16; ++j) {
            int i = t + j * 256;
            Wls[(i >> 6) * W2_STRIDE + (i & 63)] = wp[i];
        }
    } else {
        const unsigned short* wp = (const unsigned short*)W;
        #pragma unroll
        for (int j = 0; j < 16; ++j) {
            int i = t + j * 256;
            Wls[(i >> 6) * W2_STRIDE + (i & 63)] = bfu2f(wp[i]);
        }
    }
    __syncthreads();
    int col = t & 63, wv = t >> 6;
    const float* wr = Wls + col * W2_STRIDE;
    const float* xr = xs + wv * 8 * C;
    float acc[8];
    #pragma unroll
    for (int n = 0; n < 8; ++n) acc[n] = 0.f;
    #pragma unroll
    for (int kk = 0; kk < C / 4; ++kk) {
        float4 w4 = *(const float4*)(wr + kk * 4);
        #pragma unroll
        for (int n = 0; n < 8; ++n) {
            float4 x4 = *(const float4*)(xr + n * C + kk * 4);
            acc[n] += x4.x * w4.x + x4.y * w4.y + x4.z * w4.z + x4.w * w4.w;
        }
    }
    size_t obase = (size_t)blockIdx.x * 32 * C + wv * 8 * C + col;
    #pragma unroll
    for (int n = 0; n < 8; ++n) xw[obase + n * C] = f2bfu(acc[n]);
}

// ---- fused msg+update: wave per dst; bf16 gather; self-normalizing --------
// out = sigmoid( (Σ exp_e·xw[src_e]) / (Σ exp_e) + xw[d] + b )
// 2 edges/iter: half-wave per edge, dword = bf16x2 channel pair.
__global__ __launch_bounds__(256) void k_msg_csr(
    const unsigned int* __restrict__ xw, const int2* __restrict__ srt,
    const int* __restrict__ row_ptr, const void* __restrict__ b,
    const int* __restrict__ flags, void* __restrict__ outp, int out_is_final)
{
    int d = blockIdx.x * 4 + (threadIdx.x >> 6);
    int lane = threadIdx.x & 63;
    int half = lane >> 5, li = lane & 31;
    int beg = row_ptr[d], end = row_ptr[d + 1];
    float accx = 0.f, accy = 0.f, asum = 0.f;
    int j = beg;
    for (; j + 4 <= end; j += 4) {
        int2 pa = srt[j + half], pb = srt[j + 2 + half];
        float wa = __int_as_float(pa.y), wb = __int_as_float(pb.y);
        unsigned int va = xw[(size_t)pa.x * 32 + li];
        unsigned int vb = xw[(size_t)pb.x * 32 + li];
        accx += wa * bfu2f((unsigned short)(va & 0xffff))
              + wb * bfu2f((unsigned short)(vb & 0xffff));
        accy += wa * bfu2f((unsigned short)(va >> 16))
              + wb * bfu2f((unsigned short)(vb >> 16));
        asum += wa + wb;
    }
    for (; j + 2 <= end; j += 2) {
        int2 p = srt[j + half];
        float w = __int_as_float(p.y);
        unsigned int v = xw[(size_t)p.x * 32 + li];
        accx += w * bfu2f((unsigned short)(v & 0xffff));
        accy += w * bfu2f((unsigned short)(v >> 16));
        asum += w;
    }
    if (j < end && half == 0) {
        int2 p = srt[j];
        float w = __int_as_float(p.y);
        unsigned int v = xw[(size_t)p.x * 32 + li];
        accx += w * bfu2f((unsigned short)(v & 0xffff));
        accy += w * bfu2f((unsigned short)(v >> 16));
        asum += w;
    }
    accx += __shfl_xor(accx, 32);
    accy += __shfl_xor(accy, 32);
    asum += __shfl_xor(asum, 32);
    float inv = (end > beg) ? 1.f / asum : 0.f;
    unsigned int sv = xw[(size_t)d * 32 + li];
    int f32 = flags[0];
    float b0 = load_f(b, 2 * li, f32), b1 = load_f(b, 2 * li + 1, f32);
    float v0 = accx * inv + bfu2f((unsigned short)(sv & 0xffff)) + b0;
    float v1 = accy * inv + bfu2f((unsigned short)(sv >> 16))    + b1;
    float r0 = 1.f / (1.f + expf(-v0));
    float r1 = 1.f / (1.f + expf(-v1));
    if (half == 0) {
        if (out_is_final && f32) {
            ((float2*)outp)[(size_t)d * 32 + li] = make_float2(r0, r1);
        } else {
            unsigned int packed = (unsigned int)f2bfu(r0) | ((unsigned int)f2bfu(r1) << 16);
            ((unsigned int*)outp)[(size_t)d * 32 + li] = packed;
        }
    }
}

extern "C" void kernel_launch(void* const* d_in, const int* in_sizes, int n_in,
                              void* d_out, int out_size, void* d_ws, size_t ws_size,
                              hipStream_t stream) {
    const void* x  = d_in[0];
    const void* ei = d_in[1];
    const void* ea = d_in[2];
    const void* W1 = d_in[3];
    const void* b1 = d_in[4];
    const void* W2 = d_in[5];
    const void* b2 = d_in[6];

    char* base = (char*)d_ws;
    int*            flags   = (int*)base;                 // 256 B
    int*            cnt     = (int*)(base + 256);         // N
    int*            row_ptr = (int*)(base + 400256);      // N+1 (+pad)
    unsigned short* pos     = (unsigned short*)(base + 800272);  // E (2B)
    int*            bsum    = (int*)(base + 4000272);     // 25 (+pad)
    int2*           srt     = (int2*)(base + 4000528);    // E (8B-aligned)
    unsigned short* xw      = (unsigned short*)(base + 16800528); // N*64 bf16
    unsigned short* h1      = (unsigned short*)(base + 29600528); // N*64 bf16
    // total ws use ≈ 42.4 MB

    k_detect<<<1, 256, 0, stream>>>((const uint4*)x, (const int*)ei, flags);
    hipMemsetAsync(cnt, 0, 400000, stream);

    // CSR build: count+pos (1 atomic/edge), scan, atomic-free scatter
    k_hist<<<N_EDGES / 256, 256, 0, stream>>>(ei, flags, cnt, pos);
    k_scan1<<<SCAN_NB, 256, 0, stream>>>(cnt, bsum);
    k_scan3<<<SCAN_NB, 256, 0, stream>>>(cnt, bsum, row_ptr);
    k_scatter<<<N_EDGES / 256, 256, 0, stream>>>(ea, ei, flags, row_ptr, pos, srt);

    // layer 1 (internal node features bf16)
    k_gemm1<<<N_NODES / 32, 256, 0, stream>>>(x, W1, flags, xw);
    k_msg_csr<<<N_NODES / 4, 256, 0, stream>>>((const unsigned int*)xw, srt, row_ptr, b1, flags, h1, 0);

    // layer 2
    k_gemm2<<<N_NODES / 32, 256, 0, stream>>>((const unsigned int*)h1, W2, flags, xw);
    k_msg_csr<<<N_NODES / 4, 256, 0, stream>>>((const unsigned int*)xw, srt, row_ptr, b2, flags, d_out, 1);
}